// Round 11
// baseline (2052.910 us; speedup 1.0000x reference)
//
#include <hip/hip_runtime.h>
#include <hip/hip_bf16.h>
#include <math.h>

// Problem constants (fixed by the reference)
#define Nn 50000
#define Ee 400000
#define Gg 2000
#define NPGc 25
#define Hc 128
#define Lc 5
// branch row padding: 64-aligned so every GEMM tile is branch-homogeneous
#define M2c 50048              // = 64 * 782
#define R2c 100096             // = 2 * M2c

typedef __attribute__((ext_vector_type(8))) short short8;   // 8 bf16 = 4 VGPRs
typedef __attribute__((ext_vector_type(4))) float fx4;      // MFMA accumulator

__device__ inline short bf16r(float x){
  unsigned u = __float_as_uint(x);
  unsigned r = (u + 0x7fffu + ((u >> 16) & 1u)) >> 16;
  return (short)r;
}
__device__ inline float bf16f(short s){
  return __uint_as_float(((unsigned)(unsigned short)s) << 16);
}

// ------------------------------------------------------------------
// Graph preprocessing
// ------------------------------------------------------------------
__global__ void deg_kernel(const int* __restrict__ dst, int* __restrict__ deg, int E){
  int i = blockIdx.x * blockDim.x + threadIdx.x;
  if (i < E) atomicAdd(&deg[dst[i]], 1);
}

__global__ void scan1_kernel(const int* __restrict__ deg, int* __restrict__ part,
                             int* __restrict__ bsums, int n){
  __shared__ int tmp[1024];
  int b = blockIdx.x, t = threadIdx.x;
  int i = b * 1024 + t;
  int v = (i < n) ? deg[i] : 0;
  tmp[t] = v;
  __syncthreads();
  for (int off = 1; off < 1024; off <<= 1){
    int add = (t >= off) ? tmp[t - off] : 0;
    __syncthreads();
    tmp[t] += add;
    __syncthreads();
  }
  part[i] = tmp[t];
  if (t == 1023) bsums[b] = tmp[1023];
}
__global__ void scan2_kernel(int* __restrict__ bsums, int nb){
  if (threadIdx.x == 0){
    int s = 0;
    for (int i = 0; i < nb; i++){ s += bsums[i]; bsums[i] = s; }
  }
}
__global__ void scan3_kernel(const int* __restrict__ part, const int* __restrict__ bsums,
                             int* __restrict__ rowstart, int n){
  int i = blockIdx.x * blockDim.x + threadIdx.x;
  if (i == 0) rowstart[0] = 0;
  if (i < n){
    int b = i >> 10;
    int base = b ? bsums[b - 1] : 0;
    rowstart[i + 1] = part[i] + base;
  }
}

__global__ void copy_int_kernel(const int* __restrict__ a, int* __restrict__ b, int n){
  int i = blockIdx.x * blockDim.x + threadIdx.x;
  if (i < n) b[i] = a[i];
}

__global__ void scatter_kernel(const int* __restrict__ src, const int* __restrict__ dst,
                               const int* __restrict__ ef, int* cursor,
                               int* __restrict__ src_srt, int* __restrict__ code_srt, int E){
  int i = blockIdx.x * blockDim.x + threadIdx.x;
  if (i >= E) return;
  int p = atomicAdd(&cursor[dst[i]], 1);
  src_srt[p] = src[i];
  code_srt[p] = ef[i * 3 + 0] * 25 + ef[i * 3 + 1] * 5 + ef[i * 3 + 2];
}

// amp/att sized M2c; rows [Nn, M2c) are zero padding
__global__ void ampatt_kernel(const int* __restrict__ deg, float* __restrict__ amp,
                              float* __restrict__ att, int n){
  int i = blockIdx.x * blockDim.x + threadIdx.x;
  if (i >= n) return;
  if (i >= Nn){ amp[i] = 0.f; att[i] = 0.f; return; }
  float d = (float)deg[i];
  float ld = logf(d + 1.0f);
  amp[i] = ld;
  att[i] = (deg[i] > 0) ? (1.0f / ld) : 0.0f;
}

// ------------------------------------------------------------------
// Node embedding, BOTH branches stacked
// ------------------------------------------------------------------
__global__ void embed2_kernel(const int* __restrict__ nf,
                              const float* __restrict__ aemb_f,
                              const float* __restrict__ aemb_t,
                              float* __restrict__ h, short* __restrict__ h16){
  int idx = blockIdx.x * blockDim.x + threadIdx.x;
  if (idx >= R2c * Hc) return;
  int n = idx >> 7, c = idx & 127;
  int br = n >= M2c;
  int local = n - br * M2c;
  if (local >= Nn){ h[idx] = 0.f; h16[idx] = 0; return; }
  const float* aemb = br ? aemb_t : aemb_f;
  float s = 0.f;
#pragma unroll
  for (int f = 0; f < 9; f++){
    int row = nf[local * 9 + f] + 16 * f;
    s += aemb[row * Hc + c];
  }
  h[idx] = s;
  h16[idx] = bf16r(s);
}

// bsum2[b][code][c]: 125 distinct edge embeddings, both branches
__global__ void bsum2_kernel(const float* __restrict__ bemb_f, const float* __restrict__ bemb_t,
                             float* __restrict__ bsum2){
  int idx = blockIdx.x * blockDim.x + threadIdx.x;
  if (idx >= 2 * 125 * Hc) return;
  int b = idx / (125 * Hc);
  int rem = idx % (125 * Hc);
  int code = rem >> 7, c = rem & 127;
  int e0 = code / 25, e1 = (code / 5) % 5, e2 = code % 5;
  const float* bemb = b ? bemb_t : bemb_f;
  bsum2[idx] = bemb[e0 * Hc + c] + bemb[(5 + e1) * Hc + c] + bemb[(10 + e2) * Hc + c];
}

// ------------------------------------------------------------------
// up-front weight converts, both branches x 5 layers
// ------------------------------------------------------------------
__global__ void conv_pre_all_kernel(const float* __restrict__ wpre_f,
                                    const float* __restrict__ wpre_t,
                                    short* __restrict__ btpre_all){
  int idx = blockIdx.x * blockDim.x + threadIdx.x;
  if (idx >= 2 * Lc * 256 * 128) return;
  int bl = idx / (256 * 128);
  int rem = idx % (256 * 128);
  int col = rem >> 7, k = rem & 127;
  int b = bl / Lc, l = bl % Lc;
  const float* wl = (b ? wpre_t : wpre_f) + (size_t)l * 384 * 128;
  float v = (col < 128) ? wl[k * 128 + col] : wl[(128 + k) * 128 + (col - 128)];
  btpre_all[(size_t)bl * 256 * 128 + col * 128 + k] = bf16r(v);
}
__global__ void conv_post_all_kernel(const float* __restrict__ wpost_f,
                                     const float* __restrict__ wpost_t,
                                     short* __restrict__ btpost_all){
  int idx = blockIdx.x * blockDim.x + threadIdx.x;
  if (idx >= 2 * Lc * 1664 * 128) return;
  int bl = idx / (1664 * 128);
  int rem = idx % (1664 * 128);
  int k = rem >> 7, c = rem & 127;
  int b = bl / Lc, l = bl % Lc;
  const float* wl = (b ? wpost_t : wpost_f) + (size_t)l * 1664 * 128;
  btpost_all[(size_t)bl * 128 * 1664 + (size_t)c * 1664 + k] = bf16r(wl[(size_t)k * 128 + c]);
}

// ezt_all[bl][code][c] = bsum2[b][code][:] @ W_e[b,l] + b_pre[b,l]
__global__ void ezt_all_kernel(const float* __restrict__ wpre_f, const float* __restrict__ wpre_t,
                               const float* __restrict__ bpre_f, const float* __restrict__ bpre_t,
                               const float* __restrict__ bsum2, float* __restrict__ ezt_all){
  int code = blockIdx.x;
  int bl   = blockIdx.y;
  int t = threadIdx.x;
  int b = bl / Lc, l = bl % Lc;
  const float* wl = (b ? wpre_t : wpre_f) + (size_t)l * 384 * 128 + 256 * 128;
  const float* bp = (b ? bpre_t : bpre_f) + (size_t)l * 128;
  __shared__ float bs[128];
  bs[t] = bsum2[((size_t)b * 125 + code) * 128 + t];
  __syncthreads();
  float acc = bp[t];
#pragma unroll 8
  for (int k = 0; k < 128; k++) acc += bs[k] * wl[k * 128 + t];
  ezt_all[((size_t)bl * 125 + code) * 128 + t] = acc;
}

// ------------------------------------------------------------------
// Graph readout (merged): block b*Gg+g -> branch b, graph g
// ------------------------------------------------------------------
__global__ void readout2_kernel(const float* __restrict__ h,
                                float* __restrict__ r3, float* __restrict__ r2){
  int bi = blockIdx.x;
  int br = bi >= Gg;
  int g = bi - br * Gg;
  int c = threadIdx.x;
  float mn = 3.402823466e38f, mx = -3.402823466e38f, s = 0.f;
  const float* hp = h + ((size_t)br * M2c + (size_t)g * NPGc) * Hc + c;
#pragma unroll
  for (int i = 0; i < NPGc; i++){
    float v = hp[i * Hc];
    mn = fminf(mn, v); mx = fmaxf(mx, v); s += v;
  }
  float* r = br ? r2 : r3;
  r[(size_t)g * 384 + c]       = mn;
  r[(size_t)g * 384 + 128 + c] = mx;
  r[(size_t)g * 384 + 256 + c] = s * (1.0f / NPGc);
}

// ------------------------------------------------------------------
// Fused head, one graph per block
// ------------------------------------------------------------------
__global__ __launch_bounds__(256)
void head_kernel(const float* __restrict__ r2, const float* __restrict__ r3,
                 const float* __restrict__ w_out3, const float* __restrict__ b_out3,
                 const float* __restrict__ w1, const float* __restrict__ b1,
                 const float* __restrict__ w2, const float* __restrict__ b2,
                 float* __restrict__ out)
{
  __shared__ float r3_s[384];
  __shared__ float x_s[640];
  __shared__ float h1_s[128];
  __shared__ float partial[256];
  int g = blockIdx.x, t = threadIdx.x;

  for (int i = t; i < 384; i += 256){
    float v2 = r2[(size_t)g * 384 + i];
    r3_s[i] = r3[(size_t)g * 384 + i];
    x_s[i] = v2;
  }
  __syncthreads();

  {
    float acc = b_out3[t];
#pragma unroll 8
    for (int k = 0; k < 384; k++) acc += r3_s[k] * w_out3[k * 256 + t];
    x_s[384 + t] = acc;
  }
  __syncthreads();

  {
    int c = t & 127, half = t >> 7;
    float acc = half ? 0.f : b1[c];
    int kb = half * 320;
#pragma unroll 8
    for (int k = kb; k < kb + 320; k++) acc += x_s[k] * w1[k * 128 + c];
    partial[t] = acc;
  }
  __syncthreads();
  if (t < 128) h1_s[t] = fmaxf(partial[t] + partial[t + 128], 0.f);
  __syncthreads();

  {
    int c = t & 127, half = t >> 7;
    float acc = half ? 0.f : b2[c];
    int kb = half * 64;
#pragma unroll 8
    for (int k = kb; k < kb + 64; k++) acc += h1_s[k] * w2[k * 128 + c];
    partial[t] = acc;
  }
  __syncthreads();
  if (t < 128) out[(size_t)g * 128 + t] = partial[t] + partial[t + 128];
}

// ------------------------------------------------------------------
// mgemm0: bf16 MFMA GEMM, 64x128 tile, slot-decode LDS, reg prefetch.
// C16[row][NC] = A16[row][128] @ Bt(branch)^T. Merged branches.
// ------------------------------------------------------------------
__global__ __launch_bounds__(256)
void mgemm0_kernel(const short* __restrict__ A16,
                   const short* __restrict__ Bt0, const short* __restrict__ Bt1,
                   short* __restrict__ C16, int NC)
{
  const int K = 128;
  __shared__ short8 As[512];
  __shared__ short8 Bs[1024];

  int tid = threadIdx.x;
  int row0 = blockIdx.y * 64;
  int col0 = blockIdx.x * 128;
  int br = row0 >= M2c;
  const short* Bt = br ? Bt1 : Bt0;
  int wv = tid >> 6, ln = tid & 63;
  int lo = ln & 15, q = ln >> 4;

  int a_rq = (tid >> 6) & 3, a_q = (tid >> 4) & 3, a_lo = tid & 15;
  int a_grow = row0 + a_rq * 16 + a_lo;
  int b_q = (tid >> 4) & 3, b_lo = tid & 15, b_ct0 = (tid >> 6) & 3;

  fx4 acc[8];
#pragma unroll
  for (int ct = 0; ct < 8; ct++) acc[ct] = (fx4){0.f, 0.f, 0.f, 0.f};

  short8 ra[2], rb[4];
  auto loadA = [&](int k0){
#pragma unroll
    for (int i = 0; i < 2; i++)
      ra[i] = *(const short8*)(A16 + a_grow * 128 + k0 + i * 32 + a_q * 8);
  };
  auto loadB = [&](int k0){
#pragma unroll
    for (int i = 0; i < 4; i++){
      int ct = b_ct0 + (i & 1) * 4;
      int col = col0 + ct * 16 + b_lo;
      int gk = k0 + (i >> 1) * 32 + b_q * 8;
      rb[i] = *(const short8*)(Bt + col * K + gk);
    }
  };

  loadA(0); loadB(0);
  for (int k0 = 0; k0 < K; k0 += 64){
    __syncthreads();
#pragma unroll
    for (int i = 0; i < 2; i++) As[i * 256 + tid] = ra[i];
#pragma unroll
    for (int i = 0; i < 4; i++) Bs[i * 256 + tid] = rb[i];
    __syncthreads();
    int kn = k0 + 64;
    if (kn < K){ loadA(kn); loadB(kn); }
    short8 a0 = As[wv * 64 + ln];
    short8 a1 = As[256 + wv * 64 + ln];
#pragma unroll
    for (int ct = 0; ct < 8; ct++){
      short8 b0 = Bs[ct * 64 + ln];
      short8 b1 = Bs[512 + ct * 64 + ln];
      acc[ct] = __builtin_amdgcn_mfma_f32_16x16x32_bf16(a0, b0, acc[ct], 0, 0, 0);
      acc[ct] = __builtin_amdgcn_mfma_f32_16x16x32_bf16(a1, b1, acc[ct], 0, 0, 0);
    }
  }

#pragma unroll
  for (int r = 0; r < 4; r++){
    int row = row0 + wv * 16 + q * 4 + r;
#pragma unroll
    for (int ct = 0; ct < 8; ct++){
      int col = col0 + ct * 16 + lo;
      C16[(size_t)row * NC + col] = bf16r(acc[ct][r]);
    }
  }
}

// ------------------------------------------------------------------
// fused_post: PNA aggregation + post GEMM in ONE kernel.
// 32-row x 128-col tile, 3128 blocks, 256 threads = 4 waves.
// Phase 1 (NEW): wave-per-node — each wave processes its 8 nodes
//   sequentially; the full 64-lane wave covers all 128 channels
//   (2 packed bf16/lane). Coalesced 256B hsd reads per edge, uniform
//   trip count (no divergence), branchless src/code prefetch, 32-bit
//   addressing. Stats -> LDS bf16.
// Phase 2: K=1664 MFMA loop (slot-decode, reg prefetch); A k<128 from
//   global h16, k>=128 staged LDS->LDS from stats w/ amp/att scaling.
// LDS: agg 32x520x2 = 33280 + As 4096 + Bs 16384 = 53760 B.
// ------------------------------------------------------------------
__global__ __launch_bounds__(256)
void fused_post_kernel(const short* __restrict__ A16,      // h16 [R2c][128]
                       const int* __restrict__ hsdP,       // hsd16 as ints [R2c][128]
                       const short* __restrict__ Bt0, const short* __restrict__ Bt1,
                       const float* __restrict__ bias0, const float* __restrict__ bias1,
                       const float* __restrict__ ezt0, const float* __restrict__ ezt1,
                       const int* __restrict__ src_srt, const int* __restrict__ code_srt,
                       const int* __restrict__ rowstart,
                       const float* __restrict__ amp, const float* __restrict__ att,
                       const float* __restrict__ resid,    // h_cur fp32
                       float* __restrict__ C, short* __restrict__ C16)
{
  const int K = 1664, NC = 128;
  __shared__ short agg_s[32 * 520];   // [node][stat*128+ch], stride 520
  __shared__ short8 As[256];
  __shared__ short8 Bs[1024];

  int tid = threadIdx.x;
  int row0 = blockIdx.x * 32;
  int br = row0 >= M2c;
  const short* Bt = br ? Bt1 : Bt0;
  const float* bias = br ? bias1 : bias0;
  const float* ezt = br ? ezt1 : ezt0;

  int wv = tid >> 6, ln = tid & 63;

  // ================= phase 1: aggregate stats (wave-per-node) ==========
  {
    int rowbase = br * (M2c * 128);            // int ok: 6.4M
    for (int ni = 0; ni < 8; ni++){
      int node = wv * 8 + ni;
      int arow = row0 + node;
      int local = arow - br * M2c;
      int e0 = 0, e1 = 0;
      if (local < Nn){ e0 = rowstart[local]; e1 = rowstart[local + 1]; }
      int* orow = (int*)(agg_s + node * 520);
      if (e1 > e0){
        int hdp = hsdP[arow * 128 + 64 + ln];  // coalesced 256B
        float hd0 = bf16f((short)(hdp & 0xffff));
        float hd1 = bf16f((short)(((unsigned)hdp) >> 16));
        float sum0 = 0.f, sum1 = 0.f, sq0 = 0.f, sq1 = 0.f;
        float mx0 = -3.402823466e38f, mx1 = -3.402823466e38f;
        float mn0 = 3.402823466e38f,  mn1 = 3.402823466e38f;
        int sidx = src_srt[e0];
        int code = code_srt[e0];
        for (int k = e0; k < e1; k++){
          int hp = hsdP[rowbase + sidx * 128 + ln];              // coalesced 256B
          float2 ez = *(const float2*)(ezt + code * 128 + 2 * ln); // coalesced 512B
          int k2 = (k + 1 < e1) ? k + 1 : k;                     // branchless prefetch
          sidx = src_srt[k2];
          code = code_srt[k2];
          float z0 = bf16f((short)(hp & 0xffff)) + hd0 + ez.x;
          float z1 = bf16f((short)(((unsigned)hp) >> 16)) + hd1 + ez.y;
          sum0 += z0; sq0 += z0 * z0;
          mx0 = fmaxf(mx0, z0); mn0 = fminf(mn0, z0);
          sum1 += z1; sq1 += z1 * z1;
          mx1 = fmaxf(mx1, z1); mn1 = fminf(mn1, z1);
        }
        float d = (float)(e1 - e0);
        float m0 = sum0 / d, m1 = sum1 / d;
        float v0 = sq0 / d - m0 * m0; v0 = v0 > 0.f ? v0 : 0.f;
        float v1 = sq1 / d - m1 * m1; v1 = v1 > 0.f ? v1 : 0.f;
        float sd0 = sqrtf(v0 + 1e-5f), sd1 = sqrtf(v1 + 1e-5f);
        auto pack = [](float a, float b) -> int {
          return (int)(((unsigned)(unsigned short)bf16r(a)) |
                       (((unsigned)(unsigned short)bf16r(b)) << 16));
        };
        orow[ln]        = pack(m0, m1);
        orow[64 + ln]   = pack(mx0, mx1);
        orow[128 + ln]  = pack(mn0, mn1);
        orow[192 + ln]  = pack(sd0, sd1);
      } else {
        orow[ln] = 0; orow[64 + ln] = 0; orow[128 + ln] = 0; orow[192 + ln] = 0;
      }
    }
  }
  // visibility guaranteed by the K-loop barriers before first agg read (k0=128)

  // ================= phase 2: MFMA GEMM =================
  int lo = ln & 15, q = ln >> 4;
  int rh = wv >> 1, ch = wv & 1;

  int a_row = ((tid >> 6) & 1) * 16 + (tid & 15);
  int a_kofs = (tid >> 7) * 32 + ((tid >> 4) & 3) * 8;
  int a_grow = row0 + a_row;
  int local_a = a_grow - br * M2c;
  float ampv = amp[local_a], attv = att[local_a];

  int b_q = (tid >> 4) & 3, b_lo = tid & 15, b_ct0 = (tid >> 6) & 3;

  fx4 acc[4];
#pragma unroll
  for (int c4 = 0; c4 < 4; c4++) acc[c4] = (fx4){0.f, 0.f, 0.f, 0.f};

  short8 ra, rb[4];
  auto loadA_h = [&](int k0){
    ra = *(const short8*)(A16 + a_grow * 128 + k0 + a_kofs);
  };
  auto loadB = [&](int k0){
#pragma unroll
    for (int i = 0; i < 4; i++){
      int ct = b_ct0 + (i & 1) * 4;
      int col = ct * 16 + b_lo;
      int gk = k0 + (i >> 1) * 32 + b_q * 8;
      rb[i] = *(const short8*)(Bt + col * K + gk);
    }
  };

  loadA_h(0); loadB(0);
  for (int k0 = 0; k0 < K; k0 += 64){
    __syncthreads();
    // stage A
    {
      short8 va;
      if (k0 < 128){
        va = ra;
      } else {
        int base = k0 + a_kofs - 128;     // 0..1535, uniform section per thread
        int col; float sc; bool scaled;
        if (base < 512)      { col = base;        sc = 1.f;  scaled = false; }
        else if (base < 1024){ col = base - 512;  sc = ampv; scaled = true; }
        else                 { col = base - 1024; sc = attv; scaled = true; }
        va = *(const short8*)(agg_s + a_row * 520 + col);
        if (scaled){
#pragma unroll
          for (int j = 0; j < 8; j++) ((short*)&va)[j] = bf16r(bf16f(((short*)&va)[j]) * sc);
        }
      }
      As[tid] = va;
    }
#pragma unroll
    for (int i = 0; i < 4; i++) Bs[i * 256 + tid] = rb[i];
    __syncthreads();
    int kn = k0 + 64;
    if (kn < K){
      if (kn < 128) loadA_h(kn);
      loadB(kn);
    }
    short8 a0 = As[rh * 64 + ln];
    short8 a1 = As[128 + rh * 64 + ln];
#pragma unroll
    for (int c4 = 0; c4 < 4; c4++){
      int ct = ch * 4 + c4;
      short8 b0 = Bs[ct * 64 + ln];
      short8 b1 = Bs[512 + ct * 64 + ln];
      acc[c4] = __builtin_amdgcn_mfma_f32_16x16x32_bf16(a0, b0, acc[c4], 0, 0, 0);
      acc[c4] = __builtin_amdgcn_mfma_f32_16x16x32_bf16(a1, b1, acc[c4], 0, 0, 0);
    }
  }

  // epilogue
#pragma unroll
  for (int r = 0; r < 4; r++){
    int row = row0 + rh * 16 + q * 4 + r;
#pragma unroll
    for (int c4 = 0; c4 < 4; c4++){
      int col = (ch * 4 + c4) * 16 + lo;
      float v = acc[c4][r] + bias[col] + resid[(size_t)row * NC + col];
      C[(size_t)row * NC + col] = v;
      C16[(size_t)row * NC + col] = bf16r(v);
    }
  }
}

// ------------------------------------------------------------------
extern "C" void kernel_launch(void* const* d_in, const int* in_sizes, int n_in,
                              void* d_out, int out_size, void* d_ws, size_t ws_size,
                              hipStream_t stream)
{
  const int*   node_feat = (const int*)  d_in[0];
  const int*   edge_feat = (const int*)  d_in[1];
  const int*   src       = (const int*)  d_in[2];
  const int*   dst       = (const int*)  d_in[3];
  const float* aemb_f  = (const float*) d_in[5];
  const float* bemb_f  = (const float*) d_in[6];
  const float* w_pre_f = (const float*) d_in[7];
  const float* b_pre_f = (const float*) d_in[8];
  const float* w_post_f= (const float*) d_in[9];
  const float* b_post_f= (const float*) d_in[10];
  const float* w_out3  = (const float*) d_in[11];
  const float* b_out3  = (const float*) d_in[12];
  const float* aemb    = (const float*) d_in[13];
  const float* bemb    = (const float*) d_in[14];
  const float* w_pre   = (const float*) d_in[15];
  const float* b_pre   = (const float*) d_in[16];
  const float* w_post  = (const float*) d_in[17];
  const float* b_post  = (const float*) d_in[18];
  const float* w1      = (const float*) d_in[19];
  const float* b1      = (const float*) d_in[20];
  const float* w2      = (const float*) d_in[21];
  const float* b2      = (const float*) d_in[22];
  float* out = (float*)d_out;

  // ---- workspace carve ----
  char* w = (char*)d_ws;
  auto carve = [&](size_t bytes) -> void* {
    void* p = (void*)w;
    w += (bytes + 255) & ~(size_t)255;
    return p;
  };
  float* h_a       = (float*)carve((size_t)R2c * Hc * 4);
  float* h_b       = (float*)carve((size_t)R2c * Hc * 4);
  short* h16_a     = (short*)carve((size_t)R2c * Hc * 2);
  short* h16_b     = (short*)carve((size_t)R2c * Hc * 2);
  short* hsd16     = (short*)carve((size_t)R2c * 256 * 2);
  short* btpre_all = (short*)carve((size_t)2 * Lc * 256 * 128 * 2);
  short* btpost_all= (short*)carve((size_t)2 * Lc * 128 * 1664 * 2);
  float* bsum2     = (float*)carve((size_t)2 * 125 * Hc * 4);
  float* ezt_all   = (float*)carve((size_t)2 * Lc * 125 * Hc * 4);
  float* amp       = (float*)carve((size_t)M2c * 4);
  float* att       = (float*)carve((size_t)M2c * 4);
  float* r3        = (float*)carve((size_t)Gg * 384 * 4);
  float* r2        = (float*)carve((size_t)Gg * 384 * 4);
  int* deg      = (int*)carve((size_t)Nn * 4);
  int* rowstart = (int*)carve((size_t)(Nn + 1) * 4);
  int* cursor   = (int*)carve((size_t)Nn * 4);
  int* part     = (int*)carve((size_t)50176 * 4);
  int* bsums    = (int*)carve((size_t)64 * 4);
  int* src_srt  = (int*)carve((size_t)Ee * 4);
  int* code_srt = (int*)carve((size_t)Ee * 4);

  // ---- graph preprocessing ----
  hipMemsetAsync(deg, 0, (size_t)Nn * 4, stream);
  deg_kernel<<<(Ee + 255) / 256, 256, 0, stream>>>(dst, deg, Ee);
  scan1_kernel<<<49, 1024, 0, stream>>>(deg, part, bsums, Nn);
  scan2_kernel<<<1, 64, 0, stream>>>(bsums, 49);
  scan3_kernel<<<(Nn + 255) / 256, 256, 0, stream>>>(part, bsums, rowstart, Nn);
  copy_int_kernel<<<(Nn + 255) / 256, 256, 0, stream>>>(rowstart, cursor, Nn);
  scatter_kernel<<<(Ee + 255) / 256, 256, 0, stream>>>(src, dst, edge_feat, cursor,
                                                       src_srt, code_srt, Ee);
  ampatt_kernel<<<(M2c + 255) / 256, 256, 0, stream>>>(deg, amp, att, M2c);

  // ---- up-front shared tables ----
  bsum2_kernel<<<(2 * 125 * Hc + 255) / 256, 256, 0, stream>>>(bemb_f, bemb, bsum2);
  conv_pre_all_kernel<<<(2 * Lc * 256 * 128 + 255) / 256, 256, 0, stream>>>(
      w_pre_f, w_pre, btpre_all);
  conv_post_all_kernel<<<(2 * Lc * 1664 * 128 + 255) / 256, 256, 0, stream>>>(
      w_post_f, w_post, btpost_all);
  ezt_all_kernel<<<dim3(125, 2 * Lc), 128, 0, stream>>>(
      w_pre_f, w_pre, b_pre_f, b_pre, bsum2, ezt_all);

  // ---- merged-branch GNN ----
  float* h_cur = h_a;   float* h_nxt = h_b;
  short* g_cur = h16_a; short* g_nxt = h16_b;
  embed2_kernel<<<(R2c * Hc + 255) / 256, 256, 0, stream>>>(
      node_feat, aemb_f, aemb, h_cur, g_cur);

  for (int l = 0; l < Lc; l++){
    const short* pre0 = btpre_all + (size_t)(0 * Lc + l) * 256 * 128;
    const short* pre1 = btpre_all + (size_t)(1 * Lc + l) * 256 * 128;
    const short* post0 = btpost_all + (size_t)(0 * Lc + l) * 128 * 1664;
    const short* post1 = btpost_all + (size_t)(1 * Lc + l) * 128 * 1664;
    const float* ezt0 = ezt_all + (size_t)(0 * Lc + l) * 125 * Hc;
    const float* ezt1 = ezt_all + (size_t)(1 * Lc + l) * 125 * Hc;
    const float* bp0 = b_post_f + (size_t)l * 128;
    const float* bp1 = b_post   + (size_t)l * 128;

    // hsd16 = h16 @ [W_src|W_dst]
    mgemm0_kernel<<<dim3(2, R2c / 64), 256, 0, stream>>>(
        g_cur, pre0, pre1, hsd16, 256);

    // fused aggregation + post GEMM (+resid +bias), both branches
    fused_post_kernel<<<R2c / 32, 256, 0, stream>>>(
        g_cur, (const int*)hsd16, post0, post1, bp0, bp1,
        ezt0, ezt1, src_srt, code_srt, rowstart, amp, att,
        h_cur, h_nxt, g_nxt);

    { float* t = h_cur; h_cur = h_nxt; h_nxt = t; }
    { short* t = g_cur; g_cur = g_nxt; g_nxt = t; }
  }

  readout2_kernel<<<2 * Gg, 128, 0, stream>>>(h_cur, r3, r2);
  head_kernel<<<Gg, 256, 0, stream>>>(r2, r3, w_out3, b_out3, w1, b1, w2, b2, out);
}

// Round 12
// 1483.810 us; speedup vs baseline: 1.3835x; 1.3835x over previous
//
#include <hip/hip_runtime.h>
#include <hip/hip_bf16.h>
#include <math.h>

// Problem constants (fixed by the reference)
#define Nn 50000
#define Ee 400000
#define Gg 2000
#define NPGc 25
#define Hc 128
#define Lc 5
// branch row padding: 64-aligned so every GEMM tile is branch-homogeneous
#define M2c 50048              // = 64 * 782
#define R2c 100096             // = 2 * M2c

typedef __attribute__((ext_vector_type(8))) short short8;   // 8 bf16 = 4 VGPRs
typedef __attribute__((ext_vector_type(4))) float fx4;      // MFMA accumulator

__device__ inline short bf16r(float x){
  unsigned u = __float_as_uint(x);
  unsigned r = (u + 0x7fffu + ((u >> 16) & 1u)) >> 16;
  return (short)r;
}
__device__ inline float bf16f(short s){
  return __uint_as_float(((unsigned)(unsigned short)s) << 16);
}

// ------------------------------------------------------------------
// Graph preprocessing
// ------------------------------------------------------------------
__global__ void deg_kernel(const int* __restrict__ dst, int* __restrict__ deg, int E){
  int i = blockIdx.x * blockDim.x + threadIdx.x;
  if (i < E) atomicAdd(&deg[dst[i]], 1);
}

__global__ void scan1_kernel(const int* __restrict__ deg, int* __restrict__ part,
                             int* __restrict__ bsums, int n){
  __shared__ int tmp[1024];
  int b = blockIdx.x, t = threadIdx.x;
  int i = b * 1024 + t;
  int v = (i < n) ? deg[i] : 0;
  tmp[t] = v;
  __syncthreads();
  for (int off = 1; off < 1024; off <<= 1){
    int add = (t >= off) ? tmp[t - off] : 0;
    __syncthreads();
    tmp[t] += add;
    __syncthreads();
  }
  part[i] = tmp[t];
  if (t == 1023) bsums[b] = tmp[1023];
}
__global__ void scan2_kernel(int* __restrict__ bsums, int nb){
  if (threadIdx.x == 0){
    int s = 0;
    for (int i = 0; i < nb; i++){ s += bsums[i]; bsums[i] = s; }
  }
}
__global__ void scan3_kernel(const int* __restrict__ part, const int* __restrict__ bsums,
                             int* __restrict__ rowstart, int n){
  int i = blockIdx.x * blockDim.x + threadIdx.x;
  if (i == 0) rowstart[0] = 0;
  if (i < n){
    int b = i >> 10;
    int base = b ? bsums[b - 1] : 0;
    rowstart[i + 1] = part[i] + base;
  }
}

__global__ void copy_int_kernel(const int* __restrict__ a, int* __restrict__ b, int n){
  int i = blockIdx.x * blockDim.x + threadIdx.x;
  if (i < n) b[i] = a[i];
}

__global__ void scatter_kernel(const int* __restrict__ src, const int* __restrict__ dst,
                               const int* __restrict__ ef, int* cursor,
                               int* __restrict__ src_srt, int* __restrict__ code_srt, int E){
  int i = blockIdx.x * blockDim.x + threadIdx.x;
  if (i >= E) return;
  int p = atomicAdd(&cursor[dst[i]], 1);
  src_srt[p] = src[i];
  code_srt[p] = ef[i * 3 + 0] * 25 + ef[i * 3 + 1] * 5 + ef[i * 3 + 2];
}

// amp/att sized M2c; rows [Nn, M2c) are zero padding
__global__ void ampatt_kernel(const int* __restrict__ deg, float* __restrict__ amp,
                              float* __restrict__ att, int n){
  int i = blockIdx.x * blockDim.x + threadIdx.x;
  if (i >= n) return;
  if (i >= Nn){ amp[i] = 0.f; att[i] = 0.f; return; }
  float d = (float)deg[i];
  float ld = logf(d + 1.0f);
  amp[i] = ld;
  att[i] = (deg[i] > 0) ? (1.0f / ld) : 0.0f;
}

// ------------------------------------------------------------------
// Node embedding, BOTH branches stacked
// ------------------------------------------------------------------
__global__ void embed2_kernel(const int* __restrict__ nf,
                              const float* __restrict__ aemb_f,
                              const float* __restrict__ aemb_t,
                              float* __restrict__ h, short* __restrict__ h16){
  int idx = blockIdx.x * blockDim.x + threadIdx.x;
  if (idx >= R2c * Hc) return;
  int n = idx >> 7, c = idx & 127;
  int br = n >= M2c;
  int local = n - br * M2c;
  if (local >= Nn){ h[idx] = 0.f; h16[idx] = 0; return; }
  const float* aemb = br ? aemb_t : aemb_f;
  float s = 0.f;
#pragma unroll
  for (int f = 0; f < 9; f++){
    int row = nf[local * 9 + f] + 16 * f;
    s += aemb[row * Hc + c];
  }
  h[idx] = s;
  h16[idx] = bf16r(s);
}

// bsum2[b][code][c]: 125 distinct edge embeddings, both branches
__global__ void bsum2_kernel(const float* __restrict__ bemb_f, const float* __restrict__ bemb_t,
                             float* __restrict__ bsum2){
  int idx = blockIdx.x * blockDim.x + threadIdx.x;
  if (idx >= 2 * 125 * Hc) return;
  int b = idx / (125 * Hc);
  int rem = idx % (125 * Hc);
  int code = rem >> 7, c = rem & 127;
  int e0 = code / 25, e1 = (code / 5) % 5, e2 = code % 5;
  const float* bemb = b ? bemb_t : bemb_f;
  bsum2[idx] = bemb[e0 * Hc + c] + bemb[(5 + e1) * Hc + c] + bemb[(10 + e2) * Hc + c];
}

// ------------------------------------------------------------------
// up-front weight converts, both branches x 5 layers
// ------------------------------------------------------------------
__global__ void conv_pre_all_kernel(const float* __restrict__ wpre_f,
                                    const float* __restrict__ wpre_t,
                                    short* __restrict__ btpre_all){
  int idx = blockIdx.x * blockDim.x + threadIdx.x;
  if (idx >= 2 * Lc * 256 * 128) return;
  int bl = idx / (256 * 128);
  int rem = idx % (256 * 128);
  int col = rem >> 7, k = rem & 127;
  int b = bl / Lc, l = bl % Lc;
  const float* wl = (b ? wpre_t : wpre_f) + (size_t)l * 384 * 128;
  float v = (col < 128) ? wl[k * 128 + col] : wl[(128 + k) * 128 + (col - 128)];
  btpre_all[(size_t)bl * 256 * 128 + col * 128 + k] = bf16r(v);
}
__global__ void conv_post_all_kernel(const float* __restrict__ wpost_f,
                                     const float* __restrict__ wpost_t,
                                     short* __restrict__ btpost_all){
  int idx = blockIdx.x * blockDim.x + threadIdx.x;
  if (idx >= 2 * Lc * 1664 * 128) return;
  int bl = idx / (1664 * 128);
  int rem = idx % (1664 * 128);
  int k = rem >> 7, c = rem & 127;
  int b = bl / Lc, l = bl % Lc;
  const float* wl = (b ? wpost_t : wpost_f) + (size_t)l * 1664 * 128;
  btpost_all[(size_t)bl * 128 * 1664 + (size_t)c * 1664 + k] = bf16r(wl[(size_t)k * 128 + c]);
}

// ezt16_all[bl][code][c] (bf16) = bsum2[b][code][:] @ W_e[b,l] + b_pre[b,l]
__global__ void ezt_all_kernel(const float* __restrict__ wpre_f, const float* __restrict__ wpre_t,
                               const float* __restrict__ bpre_f, const float* __restrict__ bpre_t,
                               const float* __restrict__ bsum2, short* __restrict__ ezt16_all){
  int code = blockIdx.x;
  int bl   = blockIdx.y;
  int t = threadIdx.x;
  int b = bl / Lc, l = bl % Lc;
  const float* wl = (b ? wpre_t : wpre_f) + (size_t)l * 384 * 128 + 256 * 128;
  const float* bp = (b ? bpre_t : bpre_f) + (size_t)l * 128;
  __shared__ float bs[128];
  bs[t] = bsum2[((size_t)b * 125 + code) * 128 + t];
  __syncthreads();
  float acc = bp[t];
#pragma unroll 8
  for (int k = 0; k < 128; k++) acc += bs[k] * wl[k * 128 + t];
  ezt16_all[((size_t)bl * 125 + code) * 128 + t] = bf16r(acc);
}

// ------------------------------------------------------------------
// Graph readout (merged): block b*Gg+g -> branch b, graph g
// ------------------------------------------------------------------
__global__ void readout2_kernel(const float* __restrict__ h,
                                float* __restrict__ r3, float* __restrict__ r2){
  int bi = blockIdx.x;
  int br = bi >= Gg;
  int g = bi - br * Gg;
  int c = threadIdx.x;
  float mn = 3.402823466e38f, mx = -3.402823466e38f, s = 0.f;
  const float* hp = h + ((size_t)br * M2c + (size_t)g * NPGc) * Hc + c;
#pragma unroll
  for (int i = 0; i < NPGc; i++){
    float v = hp[i * Hc];
    mn = fminf(mn, v); mx = fmaxf(mx, v); s += v;
  }
  float* r = br ? r2 : r3;
  r[(size_t)g * 384 + c]       = mn;
  r[(size_t)g * 384 + 128 + c] = mx;
  r[(size_t)g * 384 + 256 + c] = s * (1.0f / NPGc);
}

// ------------------------------------------------------------------
// Fused head, one graph per block
// ------------------------------------------------------------------
__global__ __launch_bounds__(256)
void head_kernel(const float* __restrict__ r2, const float* __restrict__ r3,
                 const float* __restrict__ w_out3, const float* __restrict__ b_out3,
                 const float* __restrict__ w1, const float* __restrict__ b1,
                 const float* __restrict__ w2, const float* __restrict__ b2,
                 float* __restrict__ out)
{
  __shared__ float r3_s[384];
  __shared__ float x_s[640];
  __shared__ float h1_s[128];
  __shared__ float partial[256];
  int g = blockIdx.x, t = threadIdx.x;

  for (int i = t; i < 384; i += 256){
    float v2 = r2[(size_t)g * 384 + i];
    r3_s[i] = r3[(size_t)g * 384 + i];
    x_s[i] = v2;
  }
  __syncthreads();

  {
    float acc = b_out3[t];
#pragma unroll 8
    for (int k = 0; k < 384; k++) acc += r3_s[k] * w_out3[k * 256 + t];
    x_s[384 + t] = acc;
  }
  __syncthreads();

  {
    int c = t & 127, half = t >> 7;
    float acc = half ? 0.f : b1[c];
    int kb = half * 320;
#pragma unroll 8
    for (int k = kb; k < kb + 320; k++) acc += x_s[k] * w1[k * 128 + c];
    partial[t] = acc;
  }
  __syncthreads();
  if (t < 128) h1_s[t] = fmaxf(partial[t] + partial[t + 128], 0.f);
  __syncthreads();

  {
    int c = t & 127, half = t >> 7;
    float acc = half ? 0.f : b2[c];
    int kb = half * 64;
#pragma unroll 8
    for (int k = kb; k < kb + 64; k++) acc += h1_s[k] * w2[k * 128 + c];
    partial[t] = acc;
  }
  __syncthreads();
  if (t < 128) out[(size_t)g * 128 + t] = partial[t] + partial[t + 128];
}

// ------------------------------------------------------------------
// mgemm0: bf16 MFMA GEMM, 64x128 tile, slot-decode LDS, reg prefetch.
// C16[row][NC] = A16[row][128] @ Bt(branch)^T. Merged branches.
// ------------------------------------------------------------------
__global__ __launch_bounds__(256)
void mgemm0_kernel(const short* __restrict__ A16,
                   const short* __restrict__ Bt0, const short* __restrict__ Bt1,
                   short* __restrict__ C16, int NC)
{
  const int K = 128;
  __shared__ short8 As[512];
  __shared__ short8 Bs[1024];

  int tid = threadIdx.x;
  int row0 = blockIdx.y * 64;
  int col0 = blockIdx.x * 128;
  int br = row0 >= M2c;
  const short* Bt = br ? Bt1 : Bt0;
  int wv = tid >> 6, ln = tid & 63;
  int lo = ln & 15, q = ln >> 4;

  int a_rq = (tid >> 6) & 3, a_q = (tid >> 4) & 3, a_lo = tid & 15;
  int a_grow = row0 + a_rq * 16 + a_lo;
  int b_q = (tid >> 4) & 3, b_lo = tid & 15, b_ct0 = (tid >> 6) & 3;

  fx4 acc[8];
#pragma unroll
  for (int ct = 0; ct < 8; ct++) acc[ct] = (fx4){0.f, 0.f, 0.f, 0.f};

  short8 ra[2], rb[4];
  auto loadA = [&](int k0){
#pragma unroll
    for (int i = 0; i < 2; i++)
      ra[i] = *(const short8*)(A16 + a_grow * 128 + k0 + i * 32 + a_q * 8);
  };
  auto loadB = [&](int k0){
#pragma unroll
    for (int i = 0; i < 4; i++){
      int ct = b_ct0 + (i & 1) * 4;
      int col = col0 + ct * 16 + b_lo;
      int gk = k0 + (i >> 1) * 32 + b_q * 8;
      rb[i] = *(const short8*)(Bt + col * K + gk);
    }
  };

  loadA(0); loadB(0);
  for (int k0 = 0; k0 < K; k0 += 64){
    __syncthreads();
#pragma unroll
    for (int i = 0; i < 2; i++) As[i * 256 + tid] = ra[i];
#pragma unroll
    for (int i = 0; i < 4; i++) Bs[i * 256 + tid] = rb[i];
    __syncthreads();
    int kn = k0 + 64;
    if (kn < K){ loadA(kn); loadB(kn); }
    short8 a0 = As[wv * 64 + ln];
    short8 a1 = As[256 + wv * 64 + ln];
#pragma unroll
    for (int ct = 0; ct < 8; ct++){
      short8 b0 = Bs[ct * 64 + ln];
      short8 b1 = Bs[512 + ct * 64 + ln];
      acc[ct] = __builtin_amdgcn_mfma_f32_16x16x32_bf16(a0, b0, acc[ct], 0, 0, 0);
      acc[ct] = __builtin_amdgcn_mfma_f32_16x16x32_bf16(a1, b1, acc[ct], 0, 0, 0);
    }
  }

#pragma unroll
  for (int r = 0; r < 4; r++){
    int row = row0 + wv * 16 + q * 4 + r;
#pragma unroll
    for (int ct = 0; ct < 8; ct++){
      int col = col0 + ct * 16 + lo;
      C16[(size_t)row * NC + col] = bf16r(acc[ct][r]);
    }
  }
}

// ------------------------------------------------------------------
// fused_post: PNA aggregation + post GEMM in ONE kernel.
// 32-row x 128-col tile, 3128 blocks, 256 threads = 4 waves.
// Phase 1 (round-10 layout + pipelining): 8 threads/node, 16 ch/thread,
//   8 nodes in parallel per wave (trip = MAX degree, not sum);
//   double-buffered per-edge loads (next edge's hsd+ez issued before
//   current edge's compute); ezt packed bf16 (32KB, L1-resident);
//   32-bit addressing. Stats -> LDS bf16.
// Phase 2: K=1664 MFMA loop (slot-decode, reg prefetch); A k<128 from
//   global h16, k>=128 staged LDS->LDS from stats w/ amp/att scaling.
// LDS: agg 32x520x2 = 33280 + As 4096 + Bs 16384 = 53760 B (3 blk/CU).
// ------------------------------------------------------------------
__global__ __launch_bounds__(256)
void fused_post_kernel(const short* __restrict__ A16,      // h16 [R2c][128]
                       const int* __restrict__ hsdP,       // hsd16 as ints [R2c][128]
                       const short* __restrict__ Bt0, const short* __restrict__ Bt1,
                       const float* __restrict__ bias0, const float* __restrict__ bias1,
                       const int* __restrict__ ez16_0, const int* __restrict__ ez16_1,
                       const int* __restrict__ src_srt, const int* __restrict__ code_srt,
                       const int* __restrict__ rowstart,
                       const float* __restrict__ amp, const float* __restrict__ att,
                       const float* __restrict__ resid,    // h_cur fp32
                       float* __restrict__ C, short* __restrict__ C16)
{
  const int K = 1664, NC = 128;
  __shared__ short agg_s[32 * 520];   // [node][stat*128+ch], stride 520
  __shared__ short8 As[256];
  __shared__ short8 Bs[1024];

  int tid = threadIdx.x;
  int row0 = blockIdx.x * 32;
  int br = row0 >= M2c;
  const short* Bt = br ? Bt1 : Bt0;
  const float* bias = br ? bias1 : bias0;
  const int* ez16 = br ? ez16_1 : ez16_0;

  // ================= phase 1: aggregate stats =================
  {
    int node = tid >> 3;        // 0..31
    int sub = tid & 7;          // 8 ints = 16 channels
    int arow = row0 + node;
    int local = arow - br * M2c;
    bool have = false;
    int e0 = 0, e1 = 0;
    if (local < Nn){
      e0 = rowstart[local]; e1 = rowstart[local + 1];
      have = (e1 > e0);
    }
    short* o = agg_s + node * 520 + sub * 16;
    if (have){
      float hdv[16];
      const int* hdp = hsdP + arow * 128 + 64 + sub * 8;
#pragma unroll
      for (int i = 0; i < 8; i++){
        int p = hdp[i];
        hdv[2*i]   = bf16f((short)(p & 0xffff));
        hdv[2*i+1] = bf16f((short)(((unsigned)p) >> 16));
      }
      float sum[16], sq[16], mx[16], mn[16];
#pragma unroll
      for (int j = 0; j < 16; j++){
        sum[j] = 0.f; sq[j] = 0.f; mx[j] = -3.402823466e38f; mn[j] = 3.402823466e38f;
      }
      int rowbase = br * (M2c * 128) + sub * 8;   // 32-bit ok (< 2^31 bytes)
      int ezbase = sub * 8;
      // --- pipelined edge loop: load k+1 before computing k ---
      int pc[8], ec[8];
      {
        int sidx = src_srt[e0];
        int code = code_srt[e0];
        const int* hp = hsdP + rowbase + sidx * 128;
        const int* ep = ez16 + ezbase + code * 64;
#pragma unroll
        for (int i = 0; i < 8; i++){ pc[i] = hp[i]; ec[i] = ep[i]; }
      }
      for (int k = e0; k < e1; k++){
        int k2 = (k + 1 < e1) ? (k + 1) : k;
        int sidx_n = src_srt[k2];
        int code_n = code_srt[k2];
        const int* hpn = hsdP + rowbase + sidx_n * 128;
        const int* epn = ez16 + ezbase + code_n * 64;
        int pn[8], en[8];
#pragma unroll
        for (int i = 0; i < 8; i++){ pn[i] = hpn[i]; en[i] = epn[i]; }
        // compute with current regs while next loads are in flight
#pragma unroll
        for (int i = 0; i < 8; i++){
          int p = pc[i], e = ec[i];
          float z0 = bf16f((short)(p & 0xffff)) + hdv[2*i]
                   + bf16f((short)(e & 0xffff));
          float z1 = bf16f((short)(((unsigned)p) >> 16)) + hdv[2*i+1]
                   + bf16f((short)(((unsigned)e) >> 16));
          sum[2*i] += z0;   sq[2*i] += z0 * z0;
          mx[2*i] = fmaxf(mx[2*i], z0); mn[2*i] = fminf(mn[2*i], z0);
          sum[2*i+1] += z1; sq[2*i+1] += z1 * z1;
          mx[2*i+1] = fmaxf(mx[2*i+1], z1); mn[2*i+1] = fminf(mn[2*i+1], z1);
        }
#pragma unroll
        for (int i = 0; i < 8; i++){ pc[i] = pn[i]; ec[i] = en[i]; }
      }
      float d = (float)(e1 - e0);
#pragma unroll
      for (int j = 0; j < 16; j++){
        float m = sum[j] / d;
        float v = sq[j] / d - m * m; v = v > 0.f ? v : 0.f;
        o[j]       = bf16r(m);
        o[128 + j] = bf16r(mx[j]);
        o[256 + j] = bf16r(mn[j]);
        o[384 + j] = bf16r(sqrtf(v + 1e-5f));
      }
    } else {
#pragma unroll
      for (int j = 0; j < 16; j++){
        o[j] = 0; o[128 + j] = 0; o[256 + j] = 0; o[384 + j] = 0;
      }
    }
  }
  // visibility guaranteed by the K-loop barriers before first agg read (k0=128)

  // ================= phase 2: MFMA GEMM =================
  int wv = tid >> 6, ln = tid & 63;
  int lo = ln & 15, q = ln >> 4;
  int rh = wv >> 1, ch = wv & 1;

  int a_row = ((tid >> 6) & 1) * 16 + (tid & 15);
  int a_kofs = (tid >> 7) * 32 + ((tid >> 4) & 3) * 8;
  int a_grow = row0 + a_row;
  int local_a = a_grow - br * M2c;
  float ampv = amp[local_a], attv = att[local_a];

  int b_q = (tid >> 4) & 3, b_lo = tid & 15, b_ct0 = (tid >> 6) & 3;

  fx4 acc[4];
#pragma unroll
  for (int c4 = 0; c4 < 4; c4++) acc[c4] = (fx4){0.f, 0.f, 0.f, 0.f};

  short8 ra, rb[4];
  auto loadA_h = [&](int k0){
    ra = *(const short8*)(A16 + a_grow * 128 + k0 + a_kofs);
  };
  auto loadB = [&](int k0){
#pragma unroll
    for (int i = 0; i < 4; i++){
      int ct = b_ct0 + (i & 1) * 4;
      int col = ct * 16 + b_lo;
      int gk = k0 + (i >> 1) * 32 + b_q * 8;
      rb[i] = *(const short8*)(Bt + col * K + gk);
    }
  };

  loadA_h(0); loadB(0);
  for (int k0 = 0; k0 < K; k0 += 64){
    __syncthreads();
    // stage A
    {
      short8 va;
      if (k0 < 128){
        va = ra;
      } else {
        int base = k0 + a_kofs - 128;     // 0..1535, uniform section per thread
        int col; float sc; bool scaled;
        if (base < 512)      { col = base;        sc = 1.f;  scaled = false; }
        else if (base < 1024){ col = base - 512;  sc = ampv; scaled = true; }
        else                 { col = base - 1024; sc = attv; scaled = true; }
        va = *(const short8*)(agg_s + a_row * 520 + col);
        if (scaled){
#pragma unroll
          for (int j = 0; j < 8; j++) ((short*)&va)[j] = bf16r(bf16f(((short*)&va)[j]) * sc);
        }
      }
      As[tid] = va;
    }
#pragma unroll
    for (int i = 0; i < 4; i++) Bs[i * 256 + tid] = rb[i];
    __syncthreads();
    int kn = k0 + 64;
    if (kn < K){
      if (kn < 128) loadA_h(kn);
      loadB(kn);
    }
    short8 a0 = As[rh * 64 + ln];
    short8 a1 = As[128 + rh * 64 + ln];
#pragma unroll
    for (int c4 = 0; c4 < 4; c4++){
      int ct = ch * 4 + c4;
      short8 b0 = Bs[ct * 64 + ln];
      short8 b1 = Bs[512 + ct * 64 + ln];
      acc[c4] = __builtin_amdgcn_mfma_f32_16x16x32_bf16(a0, b0, acc[c4], 0, 0, 0);
      acc[c4] = __builtin_amdgcn_mfma_f32_16x16x32_bf16(a1, b1, acc[c4], 0, 0, 0);
    }
  }

  // epilogue
#pragma unroll
  for (int r = 0; r < 4; r++){
    int row = row0 + rh * 16 + q * 4 + r;
#pragma unroll
    for (int c4 = 0; c4 < 4; c4++){
      int col = (ch * 4 + c4) * 16 + lo;
      float v = acc[c4][r] + bias[col] + resid[(size_t)row * NC + col];
      C[(size_t)row * NC + col] = v;
      C16[(size_t)row * NC + col] = bf16r(v);
    }
  }
}

// ------------------------------------------------------------------
extern "C" void kernel_launch(void* const* d_in, const int* in_sizes, int n_in,
                              void* d_out, int out_size, void* d_ws, size_t ws_size,
                              hipStream_t stream)
{
  const int*   node_feat = (const int*)  d_in[0];
  const int*   edge_feat = (const int*)  d_in[1];
  const int*   src       = (const int*)  d_in[2];
  const int*   dst       = (const int*)  d_in[3];
  const float* aemb_f  = (const float*) d_in[5];
  const float* bemb_f  = (const float*) d_in[6];
  const float* w_pre_f = (const float*) d_in[7];
  const float* b_pre_f = (const float*) d_in[8];
  const float* w_post_f= (const float*) d_in[9];
  const float* b_post_f= (const float*) d_in[10];
  const float* w_out3  = (const float*) d_in[11];
  const float* b_out3  = (const float*) d_in[12];
  const float* aemb    = (const float*) d_in[13];
  const float* bemb    = (const float*) d_in[14];
  const float* w_pre   = (const float*) d_in[15];
  const float* b_pre   = (const float*) d_in[16];
  const float* w_post  = (const float*) d_in[17];
  const float* b_post  = (const float*) d_in[18];
  const float* w1      = (const float*) d_in[19];
  const float* b1      = (const float*) d_in[20];
  const float* w2      = (const float*) d_in[21];
  const float* b2      = (const float*) d_in[22];
  float* out = (float*)d_out;

  // ---- workspace carve ----
  char* w = (char*)d_ws;
  auto carve = [&](size_t bytes) -> void* {
    void* p = (void*)w;
    w += (bytes + 255) & ~(size_t)255;
    return p;
  };
  float* h_a       = (float*)carve((size_t)R2c * Hc * 4);
  float* h_b       = (float*)carve((size_t)R2c * Hc * 4);
  short* h16_a     = (short*)carve((size_t)R2c * Hc * 2);
  short* h16_b     = (short*)carve((size_t)R2c * Hc * 2);
  short* hsd16     = (short*)carve((size_t)R2c * 256 * 2);
  short* btpre_all = (short*)carve((size_t)2 * Lc * 256 * 128 * 2);
  short* btpost_all= (short*)carve((size_t)2 * Lc * 128 * 1664 * 2);
  float* bsum2     = (float*)carve((size_t)2 * 125 * Hc * 4);
  short* ezt16_all = (short*)carve((size_t)2 * Lc * 125 * Hc * 2);
  float* amp       = (float*)carve((size_t)M2c * 4);
  float* att       = (float*)carve((size_t)M2c * 4);
  float* r3        = (float*)carve((size_t)Gg * 384 * 4);
  float* r2        = (float*)carve((size_t)Gg * 384 * 4);
  int* deg      = (int*)carve((size_t)Nn * 4);
  int* rowstart = (int*)carve((size_t)(Nn + 1) * 4);
  int* cursor   = (int*)carve((size_t)Nn * 4);
  int* part     = (int*)carve((size_t)50176 * 4);
  int* bsums    = (int*)carve((size_t)64 * 4);
  int* src_srt  = (int*)carve((size_t)Ee * 4);
  int* code_srt = (int*)carve((size_t)Ee * 4);

  // ---- graph preprocessing ----
  hipMemsetAsync(deg, 0, (size_t)Nn * 4, stream);
  deg_kernel<<<(Ee + 255) / 256, 256, 0, stream>>>(dst, deg, Ee);
  scan1_kernel<<<49, 1024, 0, stream>>>(deg, part, bsums, Nn);
  scan2_kernel<<<1, 64, 0, stream>>>(bsums, 49);
  scan3_kernel<<<(Nn + 255) / 256, 256, 0, stream>>>(part, bsums, rowstart, Nn);
  copy_int_kernel<<<(Nn + 255) / 256, 256, 0, stream>>>(rowstart, cursor, Nn);
  scatter_kernel<<<(Ee + 255) / 256, 256, 0, stream>>>(src, dst, edge_feat, cursor,
                                                       src_srt, code_srt, Ee);
  ampatt_kernel<<<(M2c + 255) / 256, 256, 0, stream>>>(deg, amp, att, M2c);

  // ---- up-front shared tables ----
  bsum2_kernel<<<(2 * 125 * Hc + 255) / 256, 256, 0, stream>>>(bemb_f, bemb, bsum2);
  conv_pre_all_kernel<<<(2 * Lc * 256 * 128 + 255) / 256, 256, 0, stream>>>(
      w_pre_f, w_pre, btpre_all);
  conv_post_all_kernel<<<(2 * Lc * 1664 * 128 + 255) / 256, 256, 0, stream>>>(
      w_post_f, w_post, btpost_all);
  ezt_all_kernel<<<dim3(125, 2 * Lc), 128, 0, stream>>>(
      w_pre_f, w_pre, b_pre_f, b_pre, bsum2, ezt16_all);

  // ---- merged-branch GNN ----
  float* h_cur = h_a;   float* h_nxt = h_b;
  short* g_cur = h16_a; short* g_nxt = h16_b;
  embed2_kernel<<<(R2c * Hc + 255) / 256, 256, 0, stream>>>(
      node_feat, aemb_f, aemb, h_cur, g_cur);

  for (int l = 0; l < Lc; l++){
    const short* pre0 = btpre_all + (size_t)(0 * Lc + l) * 256 * 128;
    const short* pre1 = btpre_all + (size_t)(1 * Lc + l) * 256 * 128;
    const short* post0 = btpost_all + (size_t)(0 * Lc + l) * 128 * 1664;
    const short* post1 = btpost_all + (size_t)(1 * Lc + l) * 128 * 1664;
    const int* ez0 = (const int*)(ezt16_all + (size_t)(0 * Lc + l) * 125 * Hc);
    const int* ez1 = (const int*)(ezt16_all + (size_t)(1 * Lc + l) * 125 * Hc);
    const float* bp0 = b_post_f + (size_t)l * 128;
    const float* bp1 = b_post   + (size_t)l * 128;

    // hsd16 = h16 @ [W_src|W_dst]
    mgemm0_kernel<<<dim3(2, R2c / 64), 256, 0, stream>>>(
        g_cur, pre0, pre1, hsd16, 256);

    // fused aggregation + post GEMM (+resid +bias), both branches
    fused_post_kernel<<<R2c / 32, 256, 0, stream>>>(
        g_cur, (const int*)hsd16, post0, post1, bp0, bp1,
        ez0, ez1, src_srt, code_srt, rowstart, amp, att,
        h_cur, h_nxt, g_nxt);

    { float* t = h_cur; h_cur = h_nxt; h_nxt = t; }
    { short* t = g_cur; g_cur = g_nxt; g_nxt = t; }
  }

  readout2_kernel<<<2 * Gg, 128, 0, stream>>>(h_cur, r3, r2);
  head_kernel<<<Gg, 256, 0, stream>>>(r2, r3, w_out3, b_out3, w1, b1, w2, b2, out);
}